// Round 7
// baseline (367.461 us; speedup 1.0000x reference)
//
#include <hip/hip_runtime.h>
#include <stdint.h>

// ---------------------------------------------------------------------------
// MS_SSA_Conv: spiking self-attention. T=4 B=8 C=384 N=1024 heads=8.
// R10: qkv (R9 ring-of-3 reg-dbuf) and lifx FROZEN. This round attacks the
// ~180us outside qkv:
//  * kvred: ATOMIC-FREE. k*v counts are integers -> any partial-sum order is
//    bit-exact. Per-rr LDS slabs + tree sum (no LDS atomics), per-(tb,nc)
//    partial rows in r2 (no global atomics, no memset dispatch).
//  * talking: sums the 16 nc-partials (integer-exact) before the 8x8 mix.
//  * proj: old 2-barrier loop had prefetch issued AFTER MFMA (fully exposed
//    vmcnt drain) + 80 scalar BN loads/thread. Now: stage(kkb+1) issued at
//    tile TOP (drain hides under reads+MFMA, T14 issue-early), reg-dbuf both
//    k-halves, ONE barrier/tile, BN/bias via LDS tables. Same MFMA order ->
//    bit-identical output.
// ---------------------------------------------------------------------------

typedef unsigned short u16;
typedef __attribute__((ext_vector_type(8))) short short8v;
typedef __attribute__((ext_vector_type(4))) float f32x4;

#define AS1 __attribute__((address_space(1)))
#define AS3 __attribute__((address_space(3)))

__device__ __forceinline__ void async16(const void* g, void* l) {
    __builtin_amdgcn_global_load_lds((const AS1 unsigned int*)g,
                                     (AS3 unsigned int*)l, 16, 0, 0);
}
__device__ __forceinline__ f32x4 mfma_bf16(short8v a, short8v b, f32x4 c) {
    return __builtin_amdgcn_mfma_f32_16x16x32_bf16(a, b, c, 0, 0, 0);
}
__device__ __forceinline__ f32x4 mfma_f16(short8v a, short8v b, f32x4 c) {
    return __builtin_amdgcn_mfma_f32_16x16x32_f16(a, b, c, 0, 0, 0);
}

__device__ __forceinline__ u16 f2bf(float f) {  // RNE fp32->bf16
    uint32_t x = __float_as_uint(f);
    return (u16)((x + 0x7FFFu + ((x >> 16) & 1u)) >> 16);
}

#define SPIKE_H ((u16)0x3C00)  // fp16 1.0 (xs)
#define SPIKE_B ((u16)0x3F80)  // bf16 1.0 (q/k/v spikes, kvs mask)

// ---------------------------------------------------------------------------
// K0: weights. Ah [1152][768] fp16 2-part split (part-major cols);
// Aproj [384][384] bf16.
// ---------------------------------------------------------------------------
__global__ void prep_kernel(const float* __restrict__ qw, const float* __restrict__ kw,
                            const float* __restrict__ vw, const float* __restrict__ pw,
                            u16* __restrict__ Ah, u16* __restrict__ Aproj) {
    int id = blockIdx.x * 256 + threadIdx.x;
    if (id >= 1152 * 384) return;
    int m = id / 384, c = id % 384;
    int br = m / 384, o = m % 384;
    const float* W = (br == 0) ? qw : (br == 1) ? kw : vw;
    float w = W[o * 384 + c];
    union H { _Float16 h; u16 u; } u0, u1;
    u0.h = (_Float16)w;
    float r1 = w - (float)u0.h;
    u1.h = (_Float16)r1;
    u16* row = Ah + (size_t)m * 768;
    row[c] = u0.u;
    row[384 + c] = u1.u;
    if (br == 0) Aproj[o * 384 + c] = f2bf(pw[o * 384 + c]);
}

// ---------------------------------------------------------------------------
// K1: shortcut LIF on x -> xs[t,b,n,c] fp16 spikes.
// ---------------------------------------------------------------------------
__global__ __launch_bounds__(256) void lifx_kernel(const float* __restrict__ x,
                                                   u16* __restrict__ xs) {
    __shared__ u16 Tr[64 * 72];
    int b = blockIdx.z, c0 = blockIdx.y * 64, n0 = blockIdx.x * 64;
    int tid = threadIdx.x;
    int nj = (tid & 15) * 4;
    int ci = tid >> 4;
    float v[4][4];
#pragma unroll
    for (int p = 0; p < 4; p++)
#pragma unroll
        for (int e = 0; e < 4; e++) v[p][e] = 0.0f;

    for (int t = 0; t < 4; t++) {
#pragma unroll
        for (int p = 0; p < 4; p++) {
            const float* src = x + ((size_t)((t * 8 + b) * 384 + c0 + p * 16 + ci)) * 1024 + n0 + nj;
            float4 xv = *(const float4*)src;
            float xa[4] = {xv.x, xv.y, xv.z, xv.w};
#pragma unroll
            for (int e = 0; e < 4; e++) {
                float vv = v[p][e];
                vv = __fadd_rn(vv, __fmul_rn(__fsub_rn(xa[e], vv), 0.5f));
                bool sp = (vv >= 0.5f);
                v[p][e] = sp ? 0.0f : vv;
                Tr[(nj + e) * 72 + p * 16 + ci] = sp ? SPIKE_H : (u16)0;
            }
        }
        __syncthreads();
#pragma unroll
        for (int p = 0; p < 4; p++) {
            int nr = p * 16 + (tid >> 4);
            int c4 = (tid & 15) * 4;
            *(ushort4*)(xs + ((size_t)((t * 8 + b) * 1024 + n0 + nr)) * 384 + c0 + c4) =
                *(const ushort4*)&Tr[nr * 72 + c4];
        }
        __syncthreads();
    }
}

// ---------------------------------------------------------------------------
// K2: QKV conv (2-part fp16, K=768) + BN + LIF over t (from acc, epilogue).
// BM=128, BN=256 (4t x 64n), BK=64, ring-of-3 LDS slots, counted vmcnt,
// register-dbuf frag pipeline (setA=kh0, setB=kh1), ONE barrier per tile.
// 8 waves 2Mx4N (wave-tile 64x64). grid (nt=16, mt=9, b=8), 512 threads.
// ---------------------------------------------------------------------------
__global__ __launch_bounds__(512, 2) void qkv_kernel(
    const u16* __restrict__ Ah, const u16* __restrict__ xs,
    u16* __restrict__ qs, u16* __restrict__ ks, u16* __restrict__ vs,
    const float* __restrict__ qg, const float* __restrict__ qb, const float* __restrict__ qm, const float* __restrict__ qv,
    const float* __restrict__ kg, const float* __restrict__ kb, const float* __restrict__ km, const float* __restrict__ kvr,
    const float* __restrict__ vg, const float* __restrict__ vb, const float* __restrict__ vm, const float* __restrict__ vvr) {
    __shared__ __align__(16) u16 As[3][8192];    // [slot][128 rows x 64 k]
    __shared__ __align__(16) u16 Bs[3][16384];   // [slot][256 cols x 64 k]
    __shared__ float bnS[128], bnM[128], bnB[128];

    const int b = blockIdx.z, mt = blockIdx.y, nt = blockIdx.x;
    const int m0 = mt * 128, n0 = nt * 64;
    const int branch = mt / 3, o0 = (mt % 3) * 128;
    const int tid = threadIdx.x, wave = tid >> 6, lane = tid & 63;
    const int l15 = lane & 15, quad = lane >> 4;
    const int wmh = wave >> 2;   // 0/1: 64-row half
    const int wn4 = wave & 3;    // 0..3: 64-col group (4t x 16n)

    const float* g_  = (branch == 0) ? qg : (branch == 1) ? kg : vg;
    const float* be_ = (branch == 0) ? qb : (branch == 1) ? kb : vb;
    const float* m_  = (branch == 0) ? qm : (branch == 1) ? km : vm;
    const float* v_  = (branch == 0) ? qv : (branch == 1) ? kvr : vvr;
    u16* dstp = (branch == 0) ? qs : (branch == 1) ? ks : vs;

    if (tid < 128) {
        int o = o0 + tid;
        bnS[tid] = g_[o] / sqrtf(v_[o] + 1e-5f);
        bnM[tid] = m_[o];
        bnB[tid] = be_[o];
    }

    // staging: each load = 512 thr x 16B = 4096 u16 = 64 rows/cols x 128B.
    // row/col = tid>>3, chunk = tid&7; source chunk pre-swizzled (involution
    // with the read side's (kgroup ^ (row&7)) chunk select).
    const int cl = tid >> 3;                      // 0..63
    const int cs8 = ((tid & 7) ^ (cl & 7)) * 8;   // swizzled k-offset (u16)
    const int dst0 = tid * 8;                     // linear LDS dest (u16)

    const u16* pA0 = Ah + (size_t)(m0 + cl) * 768 + cs8;        // rows 0-63
    const u16* pA1 = Ah + (size_t)(m0 + 64 + cl) * 768 + cs8;   // rows 64-127
    // B col C = j*64 + cl: t = (cl>>4)&3, nl = j*16 + (cl&15)
    const int tB = (cl >> 4) & 3, nB = cl & 15;
    const u16* pB0 = xs + ((size_t)((tB * 8 + b) * 1024 + n0 +  0 + nB)) * 384 + cs8;
    const u16* pB1 = xs + ((size_t)((tB * 8 + b) * 1024 + n0 + 16 + nB)) * 384 + cs8;
    const u16* pB2 = xs + ((size_t)((tB * 8 + b) * 1024 + n0 + 32 + nB)) * 384 + cs8;
    const u16* pB3 = xs + ((size_t)((tB * 8 + b) * 1024 + n0 + 48 + nB)) * 384 + cs8;

    auto stageA = [&](int Tn, int slot) { int kk = Tn * 64;
        async16(pA0 + kk, &As[slot][dst0]);
        async16(pA1 + kk, &As[slot][4096 + dst0]); };
    auto stageB01 = [&](int Tn, int slot) { int kk = Tn * 64;
        int ck = (kk >= 384) ? kk - 384 : kk;  // 2-part split: B repeats
        async16(pB0 + ck, &Bs[slot][dst0]);
        async16(pB1 + ck, &Bs[slot][4096 + dst0]); };
    auto stageB23 = [&](int Tn, int slot) { int kk = Tn * 64;
        int ck = (kk >= 384) ? kk - 384 : kk;
        async16(pB2 + ck, &Bs[slot][8192 + dst0]);
        async16(pB3 + ck, &Bs[slot][12288 + dst0]); };

    // fragment read constants (chunk = kgroup ^ (row&7); row&7 == l15&7)
    const int ch0 = (quad ^ (l15 & 7)) * 8;        // k 0..31
    const int ch1 = ((quad + 4) ^ (l15 & 7)) * 8;  // k 32..63
    const int arow = (wmh * 64 + l15) * 64;        // + i*1024
    const int bcol = (wn4 * 64 + l15) * 64;        // + t*1024

    f32x4 acc[4][4];  // [row-frag i][t]
#pragma unroll
    for (int i = 0; i < 4; i++)
#pragma unroll
        for (int j = 0; j < 4; j++) acc[i][j] = (f32x4){0.f, 0.f, 0.f, 0.f};

    // prologue: stage tiles 0,1 (slots 0,1); publish slot 0 (counted: tile 1
    // stays in flight)
    stageA(0, 0); stageB01(0, 0); stageB23(0, 0);
    stageA(1, 1); stageB01(1, 1); stageB23(1, 1);
    asm volatile("s_waitcnt vmcnt(6)\n\ts_barrier" ::: "memory");

    short8v afA[4], bfA[4], afB[4], bfB[4];
    int r = 0, r2 = 2;
#pragma unroll 1
    for (int Tn = 0; Tn < 12; Tn++) {
        // kh0 frags -> setA (the MFMA_A critical path; issue first)
#pragma unroll
        for (int i = 0; i < 4; i++) afA[i] = *(const short8v*)&As[r][arow + i * 1024 + ch0];
#pragma unroll
        for (int t = 0; t < 4; t++) bfA[t] = *(const short8v*)&Bs[r][bcol + t * 1024 + ch0];
        __builtin_amdgcn_sched_barrier(0);
        // kh1 frags -> setB (drain under MFMA_A)
#pragma unroll
        for (int i = 0; i < 4; i++) afB[i] = *(const short8v*)&As[r][arow + i * 1024 + ch1];
#pragma unroll
        for (int t = 0; t < 4; t++) bfB[t] = *(const short8v*)&Bs[r][bcol + t * 1024 + ch1];
        // stage tile T+2 into slot r2 (its readers finished before the
        // end-of-tile barrier of Tn-1 -> race-free)
        if (Tn < 10) { stageA(Tn + 2, r2); stageB01(Tn + 2, r2); stageB23(Tn + 2, r2); }
        __builtin_amdgcn_sched_barrier(0);
        // MFMA_A: compiler's counted lgkmcnt waits only setA's 8 reads
        __builtin_amdgcn_s_setprio(1);
#pragma unroll
        for (int i = 0; i < 4; i++)
#pragma unroll
            for (int t = 0; t < 4; t++) acc[i][t] = mfma_f16(afA[i], bfA[t], acc[i][t]);
        __builtin_amdgcn_s_setprio(0);
        __builtin_amdgcn_sched_barrier(0);
        // MFMA_B: setB drained during MFMA_A
        __builtin_amdgcn_s_setprio(1);
#pragma unroll
        for (int i = 0; i < 4; i++)
#pragma unroll
            for (int t = 0; t < 4; t++) acc[i][t] = mfma_f16(afB[i], bfB[t], acc[i][t]);
        __builtin_amdgcn_s_setprio(0);
        // publish slot of tile Tn+1: tile Tn+2 (6 loads) stays in flight
        if (Tn < 10)       asm volatile("s_waitcnt vmcnt(6)\n\ts_barrier" ::: "memory");
        else if (Tn == 10) asm volatile("s_waitcnt vmcnt(0)\n\ts_barrier" ::: "memory");
        r = (r == 2) ? 0 : r + 1;
        r2 = (r2 == 2) ? 0 : r2 + 1;
    }

    // epilogue: BN + LIF over t (exact numpy order) from accumulators
    const int nn = n0 + wn4 * 16 + l15;
#pragma unroll
    for (int i = 0; i < 4; i++) {
        int co = wmh * 64 + i * 16 + quad * 4;
        float4 s4 = *(const float4*)&bnS[co];
        float4 m4 = *(const float4*)&bnM[co];
        float4 b4 = *(const float4*)&bnB[co];
        float sc[4] = {s4.x, s4.y, s4.z, s4.w};
        float mn[4] = {m4.x, m4.y, m4.z, m4.w};
        float bt[4] = {b4.x, b4.y, b4.z, b4.w};
        u16 sv[4][4];  // [t][e]
#pragma unroll
        for (int e = 0; e < 4; e++) {
            float vv = 0.0f;
#pragma unroll
            for (int t = 0; t < 4; t++) {
                float a = acc[i][t][e];
                a = __fadd_rn(__fmul_rn(__fsub_rn(a, mn[e]), sc[e]), bt[e]);
                vv = __fadd_rn(vv, __fmul_rn(__fsub_rn(a, vv), 0.5f));
                bool sp = (vv >= 0.5f);
                vv = sp ? 0.0f : vv;
                sv[t][e] = sp ? SPIKE_B : (u16)0;
            }
        }
#pragma unroll
        for (int t = 0; t < 4; t++) {
            ushort4 o4;
            o4.x = sv[t][0]; o4.y = sv[t][1]; o4.z = sv[t][2]; o4.w = sv[t][3];
            *(ushort4*)(dstp + ((size_t)((t * 8 + b) * 1024 + nn)) * 384 + o0 + co) = o4;
        }
    }
}

// ---------------------------------------------------------------------------
// K3: kv partial counts, ATOMIC-FREE. Counts are integers -> exact in fp32.
// Block (nc, tb): 384 thr, tid = rr*48 + c8. Per-rr LDS slab + tree sum,
// then one coalesced 384-float partial row to r2[tb][nc][384].
// ---------------------------------------------------------------------------
__global__ void kvred_kernel(const u16* __restrict__ ks, const u16* __restrict__ vs,
                             float* __restrict__ r2) {
    __shared__ float red[8][384];
    int tb = blockIdx.y, nc = blockIdx.x;
    int tid = threadIdx.x;
    int rr = tid / 48, c8 = tid % 48;

    float cnt[8];
#pragma unroll
    for (int e = 0; e < 8; e++) cnt[e] = 0.0f;

    size_t base = ((size_t)(tb * 1024 + nc * 64 + rr)) * 384 + c8 * 8;
#pragma unroll 2
    for (int it = 0; it < 8; it++) {
        size_t off = base + (size_t)it * 8 * 384;
        uint4 ka = *(const uint4*)(ks + off);
        uint4 va = *(const uint4*)(vs + off);
        uint32_t w0 = ka.x & va.x, w1 = ka.y & va.y, w2 = ka.z & va.z, w3 = ka.w & va.w;
        const uint32_t S = SPIKE_B;
        if ((w0 & 0xFFFFu) == S) cnt[0] += 1.0f;
        if ((w0 >> 16) == S)     cnt[1] += 1.0f;
        if ((w1 & 0xFFFFu) == S) cnt[2] += 1.0f;
        if ((w1 >> 16) == S)     cnt[3] += 1.0f;
        if ((w2 & 0xFFFFu) == S) cnt[4] += 1.0f;
        if ((w2 >> 16) == S)     cnt[5] += 1.0f;
        if ((w3 & 0xFFFFu) == S) cnt[6] += 1.0f;
        if ((w3 >> 16) == S)     cnt[7] += 1.0f;
    }
#pragma unroll
    for (int e = 0; e < 8; e++) red[rr][c8 * 8 + e] = cnt[e];  // unique slots
    __syncthreads();
    float s = 0.0f;
#pragma unroll
    for (int q = 0; q < 8; q++) s += red[q][tid];
    r2[((size_t)(tb * 16 + nc)) * 384 + tid] = s;  // coalesced, no atomics
}

// K4: talking heads (8x8 fp32) + LIF over t -> kvs[t,b,c] bf16 {0,1} mask.
// Sums the 16 per-nc partials (integer counts -> exact, order-free).
__global__ void talking_kernel(const float* __restrict__ r2, const float* __restrict__ th,
                               u16* __restrict__ kvs) {
    int id = blockIdx.x * 256 + threadIdx.x;
    if (id >= 8 * 384) return;
    int b = id / 384, c = id % 384;
    int oh = c / 48, d = c % 48;
    float v = 0.0f;
    for (int t = 0; t < 4; t++) {
        const float* rr = r2 + ((size_t)((t * 8 + b) * 16)) * 384 + d;
        float s = 0.0f;
#pragma unroll
        for (int h = 0; h < 8; h++) {
            float kvsum = 0.0f;
#pragma unroll
            for (int nc = 0; nc < 16; nc++) kvsum += rr[nc * 384 + h * 48];
            s = __fmaf_rn(th[oh * 8 + h], kvsum, s);
        }
        v = __fadd_rn(v, __fmul_rn(__fsub_rn(s, v), 0.5f));
        bool sp = (v >= 0.5f);
        v = sp ? 0.0f : v;
        kvs[(t * 8 + b) * 384 + c] = sp ? SPIKE_B : (u16)0;
    }
}

// ---------------------------------------------------------------------------
// K5: proj conv (K=384 bf16) + fused kvs gate + bias + BN + residual.
// 128x128 tiles, ring-of-2, issue-early prefetch (T14), reg-dbuf k-halves,
// ONE barrier/tile, BN tables in LDS. grid (nt=8, mt=3, tb=32), 2 blk/CU.
// ---------------------------------------------------------------------------
__global__ __launch_bounds__(256, 2) void proj_kernel(
    const u16* __restrict__ Aproj, const u16* __restrict__ qs, const u16* __restrict__ kvs,
    const float* __restrict__ xin,
    const float* __restrict__ pb, const float* __restrict__ pg, const float* __restrict__ pbe,
    const float* __restrict__ pm, const float* __restrict__ pv, float* __restrict__ out) {
    __shared__ __align__(16) u16 At[2][8192];
    __shared__ __align__(16) u16 Bt[2][8192];
    __shared__ float eS[128], eM[128], eB[128], eBi[128];

    int tb = blockIdx.z, mt = blockIdx.y, nt = blockIdx.x;
    int m0 = mt * 128, n0 = nt * 128;
    int tid = threadIdx.x, wave = tid >> 6, lane = tid & 63;
    int l15 = lane & 15, quad = lane >> 4;
    int wm = (wave & 1) * 64, wn = (wave >> 1) * 64;

    const u16* Bsrc = qs + ((size_t)(tb * 1024 + n0)) * 384;
    const u16* mbase = kvs + tb * 384;

    if (tid < 128) {
        int o = m0 + tid;
        eS[tid] = pg[o] / sqrtf(pv[o] + 1e-5f);
        eM[tid] = pm[o];
        eB[tid] = pbe[o];
        eBi[tid] = pb[o];
    }

    auto stage = [&](int s) {
        int kk = s * 64;
        int buf = s & 1;
#pragma unroll
        for (int ii = 0; ii < 4; ii++) {
            int l = ii * 256 + tid;
            int row = l >> 3;
            int cs = (l & 7) ^ (row & 7);
            async16(Aproj + (size_t)(m0 + row) * 384 + kk + cs * 8, &At[buf][l * 8]);
            async16(Bsrc + (size_t)row * 384 + kk + cs * 8, &Bt[buf][l * 8]);
        }
    };

    f32x4 acc[4][4];
#pragma unroll
    for (int i = 0; i < 4; i++)
#pragma unroll
        for (int j = 0; j < 4; j++) acc[i][j] = (f32x4){0.f, 0.f, 0.f, 0.f};

    stage(0);
    __syncthreads();  // stage0 landed + tables published

#pragma unroll 1
    for (int kkb = 0; kkb < 6; kkb++) {
        int buf = kkb & 1;
        int kk = kkb * 64;
        // issue next tile FIRST: its vmcnt(0) drain at tile end hides under
        // this tile's reads + 32 MFMAs (buf^1's readers done at end of kkb-1)
        if (kkb < 5) stage(kkb + 1);
        __builtin_amdgcn_sched_barrier(0);

        short8v msk0 = *(const short8v*)(mbase + kk + quad * 8);
        short8v msk1 = *(const short8v*)(mbase + kk + (4 + quad) * 8);
        short8v afA[4], bfA[4], afB[4], bfB[4];
#pragma unroll
        for (int i = 0; i < 4; i++) {
            int row = wm + i * 16 + l15;
            afA[i] = *(const short8v*)&At[buf][row * 64 + ((quad) ^ (row & 7)) * 8];
            afB[i] = *(const short8v*)&At[buf][row * 64 + ((4 + quad) ^ (row & 7)) * 8];
        }
#pragma unroll
        for (int j = 0; j < 4; j++) {
            int nr = wn + j * 16 + l15;
            bfA[j] = *(const short8v*)&Bt[buf][nr * 64 + ((quad) ^ (nr & 7)) * 8] & msk0;
            bfB[j] = *(const short8v*)&Bt[buf][nr * 64 + ((4 + quad) ^ (nr & 7)) * 8] & msk1;
        }
        __builtin_amdgcn_sched_barrier(0);
        __builtin_amdgcn_s_setprio(1);
#pragma unroll
        for (int i = 0; i < 4; i++)
#pragma unroll
            for (int j = 0; j < 4; j++) acc[i][j] = mfma_bf16(afA[i], bfA[j], acc[i][j]);
        __builtin_amdgcn_s_setprio(0);
        __builtin_amdgcn_sched_barrier(0);
        __builtin_amdgcn_s_setprio(1);
#pragma unroll
        for (int i = 0; i < 4; i++)
#pragma unroll
            for (int j = 0; j < 4; j++) acc[i][j] = mfma_bf16(afB[i], bfB[j], acc[i][j]);
        __builtin_amdgcn_s_setprio(0);
        // publish buf^1 for tile kkb+1 (ring-of-2: nothing newer to count)
        if (kkb < 5) asm volatile("s_waitcnt vmcnt(0)\n\ts_barrier" ::: "memory");
    }

    // epilogue: y = conv+bias; (y-mean)*scale+beta; + identity (numpy order)
#pragma unroll
    for (int i = 0; i < 4; i++) {
#pragma unroll
        for (int e = 0; e < 4; e++) {
            int co = wm + i * 16 + quad * 4 + e;
            int o = m0 + co;
            float scale = eS[co], mean = eM[co], beta = eB[co], bias = eBi[co];
#pragma unroll
            for (int j = 0; j < 4; j++) {
                int n = n0 + wn + j * 16 + l15;
                size_t idx = ((size_t)tb * 384 + o) * 1024 + n;
                float y = __fadd_rn(acc[i][j][e], bias);
                y = __fadd_rn(__fmul_rn(__fsub_rn(y, mean), scale), beta);
                out[idx] = __fadd_rn(y, xin[idx]);
            }
        }
    }
}

// ---------------------------------------------------------------------------
extern "C" void kernel_launch(void* const* d_in, const int* in_sizes, int n_in,
                              void* d_out, int out_size, void* d_ws, size_t ws_size,
                              hipStream_t stream) {
    (void)in_sizes; (void)n_in; (void)out_size; (void)ws_size;
    const float* x  = (const float*)d_in[0];
    const float* qw = (const float*)d_in[1];
    const float* kw = (const float*)d_in[2];
    const float* vw = (const float*)d_in[3];
    const float* th = (const float*)d_in[4];
    const float* pw = (const float*)d_in[5];
    const float* pb = (const float*)d_in[6];
    const float* qg = (const float*)d_in[7],  *qbe = (const float*)d_in[8];
    const float* qm = (const float*)d_in[9],  *qv  = (const float*)d_in[10];
    const float* kg = (const float*)d_in[11], *kbe = (const float*)d_in[12];
    const float* km = (const float*)d_in[13], *kv_ = (const float*)d_in[14];
    const float* vg = (const float*)d_in[15], *vbe = (const float*)d_in[16];
    const float* vm = (const float*)d_in[17], *vv_ = (const float*)d_in[18];
    const float* pg = (const float*)d_in[19], *pbe = (const float*)d_in[20];
    const float* pm = (const float*)d_in[21], *pv  = (const float*)d_in[22];
    float* out = (float*)d_out;

    char* w = (char*)d_ws;
    const size_t SPIKES = (size_t)32 * 1024 * 384 * 2;  // 25,165,824 B each
    u16* xs    = (u16*)(w);
    u16* qs    = (u16*)(w + SPIKES);
    u16* ks    = (u16*)(w + 2 * SPIKES);
    u16* vs    = (u16*)(w + 3 * SPIKES);
    u16* Ah    = (u16*)(w + 4 * SPIKES);                         // 1,769,472 B
    u16* Aproj = (u16*)(w + 4 * SPIKES + 1769472);               //   294,912 B
    float* r2  = (float*)(w + 4 * SPIKES + 1769472 + 294912);    //   786,432 B
    u16* kvs   = (u16*)(w + 4 * SPIKES + 1769472 + 294912 + 786432);  // 24,576 B

    prep_kernel<<<1728, 256, 0, stream>>>(qw, kw, vw, pw, Ah, Aproj);
    lifx_kernel<<<dim3(16, 6, 8), 256, 0, stream>>>(x, xs);
    qkv_kernel<<<dim3(16, 9, 8), 512, 0, stream>>>(Ah, xs, qs, ks, vs,
                                                   qg, qbe, qm, qv,
                                                   kg, kbe, km, kv_,
                                                   vg, vbe, vm, vv_);
    kvred_kernel<<<dim3(16, 32), 384, 0, stream>>>(ks, vs, r2);
    talking_kernel<<<12, 256, 0, stream>>>(r2, th, kvs);
    proj_kernel<<<dim3(8, 3, 32), 256, 0, stream>>>(Aproj, qs, kvs, x, pb, pg, pbe, pm, pv, out);
}

// Round 8
// 251.178 us; speedup vs baseline: 1.4629x; 1.4629x over previous
//
#include <hip/hip_runtime.h>
#include <stdint.h>

// ---------------------------------------------------------------------------
// MS_SSA_Conv: spiking self-attention. T=4 B=8 C=384 N=1024 heads=8.
// R11 = R10 with the talking-kernel latency disaster fixed:
//   R10 post-mortem: talking read r2 with 512 strided scalar loads/thread on
//   a 12-block grid -> fully latency-serialized (127us, was 5.5). Fix: tiny
//   ncsum_kernel (coalesced, 48 blocks) pre-reduces r2 over nc -> r; talking
//   reverts to the cheap 32-load form. Integer counts -> order-free exact.
//   kvred (atomic-free) and proj (issue-early ring-of-2, one barrier/tile,
//   BN tables) kept from R10. qkv (R9 ring-of-3 reg-dbuf) and lifx frozen.
// ---------------------------------------------------------------------------

typedef unsigned short u16;
typedef __attribute__((ext_vector_type(8))) short short8v;
typedef __attribute__((ext_vector_type(4))) float f32x4;

#define AS1 __attribute__((address_space(1)))
#define AS3 __attribute__((address_space(3)))

__device__ __forceinline__ void async16(const void* g, void* l) {
    __builtin_amdgcn_global_load_lds((const AS1 unsigned int*)g,
                                     (AS3 unsigned int*)l, 16, 0, 0);
}
__device__ __forceinline__ f32x4 mfma_bf16(short8v a, short8v b, f32x4 c) {
    return __builtin_amdgcn_mfma_f32_16x16x32_bf16(a, b, c, 0, 0, 0);
}
__device__ __forceinline__ f32x4 mfma_f16(short8v a, short8v b, f32x4 c) {
    return __builtin_amdgcn_mfma_f32_16x16x32_f16(a, b, c, 0, 0, 0);
}

__device__ __forceinline__ u16 f2bf(float f) {  // RNE fp32->bf16
    uint32_t x = __float_as_uint(f);
    return (u16)((x + 0x7FFFu + ((x >> 16) & 1u)) >> 16);
}

#define SPIKE_H ((u16)0x3C00)  // fp16 1.0 (xs)
#define SPIKE_B ((u16)0x3F80)  // bf16 1.0 (q/k/v spikes, kvs mask)

// ---------------------------------------------------------------------------
// K0: weights. Ah [1152][768] fp16 2-part split (part-major cols);
// Aproj [384][384] bf16.
// ---------------------------------------------------------------------------
__global__ void prep_kernel(const float* __restrict__ qw, const float* __restrict__ kw,
                            const float* __restrict__ vw, const float* __restrict__ pw,
                            u16* __restrict__ Ah, u16* __restrict__ Aproj) {
    int id = blockIdx.x * 256 + threadIdx.x;
    if (id >= 1152 * 384) return;
    int m = id / 384, c = id % 384;
    int br = m / 384, o = m % 384;
    const float* W = (br == 0) ? qw : (br == 1) ? kw : vw;
    float w = W[o * 384 + c];
    union H { _Float16 h; u16 u; } u0, u1;
    u0.h = (_Float16)w;
    float r1 = w - (float)u0.h;
    u1.h = (_Float16)r1;
    u16* row = Ah + (size_t)m * 768;
    row[c] = u0.u;
    row[384 + c] = u1.u;
    if (br == 0) Aproj[o * 384 + c] = f2bf(pw[o * 384 + c]);
}

// ---------------------------------------------------------------------------
// K1: shortcut LIF on x -> xs[t,b,n,c] fp16 spikes.
// ---------------------------------------------------------------------------
__global__ __launch_bounds__(256) void lifx_kernel(const float* __restrict__ x,
                                                   u16* __restrict__ xs) {
    __shared__ u16 Tr[64 * 72];
    int b = blockIdx.z, c0 = blockIdx.y * 64, n0 = blockIdx.x * 64;
    int tid = threadIdx.x;
    int nj = (tid & 15) * 4;
    int ci = tid >> 4;
    float v[4][4];
#pragma unroll
    for (int p = 0; p < 4; p++)
#pragma unroll
        for (int e = 0; e < 4; e++) v[p][e] = 0.0f;

    for (int t = 0; t < 4; t++) {
#pragma unroll
        for (int p = 0; p < 4; p++) {
            const float* src = x + ((size_t)((t * 8 + b) * 384 + c0 + p * 16 + ci)) * 1024 + n0 + nj;
            float4 xv = *(const float4*)src;
            float xa[4] = {xv.x, xv.y, xv.z, xv.w};
#pragma unroll
            for (int e = 0; e < 4; e++) {
                float vv = v[p][e];
                vv = __fadd_rn(vv, __fmul_rn(__fsub_rn(xa[e], vv), 0.5f));
                bool sp = (vv >= 0.5f);
                v[p][e] = sp ? 0.0f : vv;
                Tr[(nj + e) * 72 + p * 16 + ci] = sp ? SPIKE_H : (u16)0;
            }
        }
        __syncthreads();
#pragma unroll
        for (int p = 0; p < 4; p++) {
            int nr = p * 16 + (tid >> 4);
            int c4 = (tid & 15) * 4;
            *(ushort4*)(xs + ((size_t)((t * 8 + b) * 1024 + n0 + nr)) * 384 + c0 + c4) =
                *(const ushort4*)&Tr[nr * 72 + c4];
        }
        __syncthreads();
    }
}

// ---------------------------------------------------------------------------
// K2: QKV conv (2-part fp16, K=768) + BN + LIF over t (from acc, epilogue).
// BM=128, BN=256 (4t x 64n), BK=64, ring-of-3 LDS slots, counted vmcnt,
// register-dbuf frag pipeline (setA=kh0, setB=kh1), ONE barrier per tile.
// 8 waves 2Mx4N (wave-tile 64x64). grid (nt=16, mt=9, b=8), 512 threads.
// ---------------------------------------------------------------------------
__global__ __launch_bounds__(512, 2) void qkv_kernel(
    const u16* __restrict__ Ah, const u16* __restrict__ xs,
    u16* __restrict__ qs, u16* __restrict__ ks, u16* __restrict__ vs,
    const float* __restrict__ qg, const float* __restrict__ qb, const float* __restrict__ qm, const float* __restrict__ qv,
    const float* __restrict__ kg, const float* __restrict__ kb, const float* __restrict__ km, const float* __restrict__ kvr,
    const float* __restrict__ vg, const float* __restrict__ vb, const float* __restrict__ vm, const float* __restrict__ vvr) {
    __shared__ __align__(16) u16 As[3][8192];    // [slot][128 rows x 64 k]
    __shared__ __align__(16) u16 Bs[3][16384];   // [slot][256 cols x 64 k]
    __shared__ float bnS[128], bnM[128], bnB[128];

    const int b = blockIdx.z, mt = blockIdx.y, nt = blockIdx.x;
    const int m0 = mt * 128, n0 = nt * 64;
    const int branch = mt / 3, o0 = (mt % 3) * 128;
    const int tid = threadIdx.x, wave = tid >> 6, lane = tid & 63;
    const int l15 = lane & 15, quad = lane >> 4;
    const int wmh = wave >> 2;   // 0/1: 64-row half
    const int wn4 = wave & 3;    // 0..3: 64-col group (4t x 16n)

    const float* g_  = (branch == 0) ? qg : (branch == 1) ? kg : vg;
    const float* be_ = (branch == 0) ? qb : (branch == 1) ? kb : vb;
    const float* m_  = (branch == 0) ? qm : (branch == 1) ? km : vm;
    const float* v_  = (branch == 0) ? qv : (branch == 1) ? kvr : vvr;
    u16* dstp = (branch == 0) ? qs : (branch == 1) ? ks : vs;

    if (tid < 128) {
        int o = o0 + tid;
        bnS[tid] = g_[o] / sqrtf(v_[o] + 1e-5f);
        bnM[tid] = m_[o];
        bnB[tid] = be_[o];
    }

    // staging: each load = 512 thr x 16B = 4096 u16 = 64 rows/cols x 128B.
    // row/col = tid>>3, chunk = tid&7; source chunk pre-swizzled (involution
    // with the read side's (kgroup ^ (row&7)) chunk select).
    const int cl = tid >> 3;                      // 0..63
    const int cs8 = ((tid & 7) ^ (cl & 7)) * 8;   // swizzled k-offset (u16)
    const int dst0 = tid * 8;                     // linear LDS dest (u16)

    const u16* pA0 = Ah + (size_t)(m0 + cl) * 768 + cs8;        // rows 0-63
    const u16* pA1 = Ah + (size_t)(m0 + 64 + cl) * 768 + cs8;   // rows 64-127
    // B col C = j*64 + cl: t = (cl>>4)&3, nl = j*16 + (cl&15)
    const int tB = (cl >> 4) & 3, nB = cl & 15;
    const u16* pB0 = xs + ((size_t)((tB * 8 + b) * 1024 + n0 +  0 + nB)) * 384 + cs8;
    const u16* pB1 = xs + ((size_t)((tB * 8 + b) * 1024 + n0 + 16 + nB)) * 384 + cs8;
    const u16* pB2 = xs + ((size_t)((tB * 8 + b) * 1024 + n0 + 32 + nB)) * 384 + cs8;
    const u16* pB3 = xs + ((size_t)((tB * 8 + b) * 1024 + n0 + 48 + nB)) * 384 + cs8;

    auto stageA = [&](int Tn, int slot) { int kk = Tn * 64;
        async16(pA0 + kk, &As[slot][dst0]);
        async16(pA1 + kk, &As[slot][4096 + dst0]); };
    auto stageB01 = [&](int Tn, int slot) { int kk = Tn * 64;
        int ck = (kk >= 384) ? kk - 384 : kk;  // 2-part split: B repeats
        async16(pB0 + ck, &Bs[slot][dst0]);
        async16(pB1 + ck, &Bs[slot][4096 + dst0]); };
    auto stageB23 = [&](int Tn, int slot) { int kk = Tn * 64;
        int ck = (kk >= 384) ? kk - 384 : kk;
        async16(pB2 + ck, &Bs[slot][8192 + dst0]);
        async16(pB3 + ck, &Bs[slot][12288 + dst0]); };

    // fragment read constants (chunk = kgroup ^ (row&7); row&7 == l15&7)
    const int ch0 = (quad ^ (l15 & 7)) * 8;        // k 0..31
    const int ch1 = ((quad + 4) ^ (l15 & 7)) * 8;  // k 32..63
    const int arow = (wmh * 64 + l15) * 64;        // + i*1024
    const int bcol = (wn4 * 64 + l15) * 64;        // + t*1024

    f32x4 acc[4][4];  // [row-frag i][t]
#pragma unroll
    for (int i = 0; i < 4; i++)
#pragma unroll
        for (int j = 0; j < 4; j++) acc[i][j] = (f32x4){0.f, 0.f, 0.f, 0.f};

    // prologue: stage tiles 0,1 (slots 0,1); publish slot 0 (counted: tile 1
    // stays in flight)
    stageA(0, 0); stageB01(0, 0); stageB23(0, 0);
    stageA(1, 1); stageB01(1, 1); stageB23(1, 1);
    asm volatile("s_waitcnt vmcnt(6)\n\ts_barrier" ::: "memory");

    short8v afA[4], bfA[4], afB[4], bfB[4];
    int r = 0, r2 = 2;
#pragma unroll 1
    for (int Tn = 0; Tn < 12; Tn++) {
        // kh0 frags -> setA (the MFMA_A critical path; issue first)
#pragma unroll
        for (int i = 0; i < 4; i++) afA[i] = *(const short8v*)&As[r][arow + i * 1024 + ch0];
#pragma unroll
        for (int t = 0; t < 4; t++) bfA[t] = *(const short8v*)&Bs[r][bcol + t * 1024 + ch0];
        __builtin_amdgcn_sched_barrier(0);
        // kh1 frags -> setB (drain under MFMA_A)
#pragma unroll
        for (int i = 0; i < 4; i++) afB[i] = *(const short8v*)&As[r][arow + i * 1024 + ch1];
#pragma unroll
        for (int t = 0; t < 4; t++) bfB[t] = *(const short8v*)&Bs[r][bcol + t * 1024 + ch1];
        // stage tile T+2 into slot r2 (its readers finished before the
        // end-of-tile barrier of Tn-1 -> race-free)
        if (Tn < 10) { stageA(Tn + 2, r2); stageB01(Tn + 2, r2); stageB23(Tn + 2, r2); }
        __builtin_amdgcn_sched_barrier(0);
        // MFMA_A: compiler's counted lgkmcnt waits only setA's 8 reads
        __builtin_amdgcn_s_setprio(1);
#pragma unroll
        for (int i = 0; i < 4; i++)
#pragma unroll
            for (int t = 0; t < 4; t++) acc[i][t] = mfma_f16(afA[i], bfA[t], acc[i][t]);
        __builtin_amdgcn_s_setprio(0);
        __builtin_amdgcn_sched_barrier(0);
        // MFMA_B: setB drained during MFMA_A
        __builtin_amdgcn_s_setprio(1);
#pragma unroll
        for (int i = 0; i < 4; i++)
#pragma unroll
            for (int t = 0; t < 4; t++) acc[i][t] = mfma_f16(afB[i], bfB[t], acc[i][t]);
        __builtin_amdgcn_s_setprio(0);
        // publish slot of tile Tn+1: tile Tn+2 (6 loads) stays in flight
        if (Tn < 10)       asm volatile("s_waitcnt vmcnt(6)\n\ts_barrier" ::: "memory");
        else if (Tn == 10) asm volatile("s_waitcnt vmcnt(0)\n\ts_barrier" ::: "memory");
        r = (r == 2) ? 0 : r + 1;
        r2 = (r2 == 2) ? 0 : r2 + 1;
    }

    // epilogue: BN + LIF over t (exact numpy order) from accumulators
    const int nn = n0 + wn4 * 16 + l15;
#pragma unroll
    for (int i = 0; i < 4; i++) {
        int co = wmh * 64 + i * 16 + quad * 4;
        float4 s4 = *(const float4*)&bnS[co];
        float4 m4 = *(const float4*)&bnM[co];
        float4 b4 = *(const float4*)&bnB[co];
        float sc[4] = {s4.x, s4.y, s4.z, s4.w};
        float mn[4] = {m4.x, m4.y, m4.z, m4.w};
        float bt[4] = {b4.x, b4.y, b4.z, b4.w};
        u16 sv[4][4];  // [t][e]
#pragma unroll
        for (int e = 0; e < 4; e++) {
            float vv = 0.0f;
#pragma unroll
            for (int t = 0; t < 4; t++) {
                float a = acc[i][t][e];
                a = __fadd_rn(__fmul_rn(__fsub_rn(a, mn[e]), sc[e]), bt[e]);
                vv = __fadd_rn(vv, __fmul_rn(__fsub_rn(a, vv), 0.5f));
                bool sp = (vv >= 0.5f);
                vv = sp ? 0.0f : vv;
                sv[t][e] = sp ? SPIKE_B : (u16)0;
            }
        }
#pragma unroll
        for (int t = 0; t < 4; t++) {
            ushort4 o4;
            o4.x = sv[t][0]; o4.y = sv[t][1]; o4.z = sv[t][2]; o4.w = sv[t][3];
            *(ushort4*)(dstp + ((size_t)((t * 8 + b) * 1024 + nn)) * 384 + o0 + co) = o4;
        }
    }
}

// ---------------------------------------------------------------------------
// K3: kv partial counts, ATOMIC-FREE. Counts are integers -> exact in fp32.
// Block (nc, tb): 384 thr, tid = rr*48 + c8. Per-rr LDS slab + tree sum,
// then one coalesced 384-float partial row to r2[tb][nc][384].
// ---------------------------------------------------------------------------
__global__ void kvred_kernel(const u16* __restrict__ ks, const u16* __restrict__ vs,
                             float* __restrict__ r2) {
    __shared__ float red[8][384];
    int tb = blockIdx.y, nc = blockIdx.x;
    int tid = threadIdx.x;
    int rr = tid / 48, c8 = tid % 48;

    float cnt[8];
#pragma unroll
    for (int e = 0; e < 8; e++) cnt[e] = 0.0f;

    size_t base = ((size_t)(tb * 1024 + nc * 64 + rr)) * 384 + c8 * 8;
#pragma unroll 2
    for (int it = 0; it < 8; it++) {
        size_t off = base + (size_t)it * 8 * 384;
        uint4 ka = *(const uint4*)(ks + off);
        uint4 va = *(const uint4*)(vs + off);
        uint32_t w0 = ka.x & va.x, w1 = ka.y & va.y, w2 = ka.z & va.z, w3 = ka.w & va.w;
        const uint32_t S = SPIKE_B;
        if ((w0 & 0xFFFFu) == S) cnt[0] += 1.0f;
        if ((w0 >> 16) == S)     cnt[1] += 1.0f;
        if ((w1 & 0xFFFFu) == S) cnt[2] += 1.0f;
        if ((w1 >> 16) == S)     cnt[3] += 1.0f;
        if ((w2 & 0xFFFFu) == S) cnt[4] += 1.0f;
        if ((w2 >> 16) == S)     cnt[5] += 1.0f;
        if ((w3 & 0xFFFFu) == S) cnt[6] += 1.0f;
        if ((w3 >> 16) == S)     cnt[7] += 1.0f;
    }
#pragma unroll
    for (int e = 0; e < 8; e++) red[rr][c8 * 8 + e] = cnt[e];  // unique slots
    __syncthreads();
    float s = 0.0f;
#pragma unroll
    for (int q = 0; q < 8; q++) s += red[q][tid];
    r2[((size_t)(tb * 16 + nc)) * 384 + tid] = s;  // coalesced, no atomics
}

// K3b: r[tb][c] = sum_nc r2[tb][nc][c]. Coalesced over c, 16 independent
// loads/thread, 48 blocks. Integer counts -> order-free exact.
__global__ void ncsum_kernel(const float* __restrict__ r2, float* __restrict__ r) {
    int id = blockIdx.x * 256 + threadIdx.x;
    if (id >= 32 * 384) return;
    int tb = id / 384, c = id % 384;
    const float* p = r2 + ((size_t)(tb * 16)) * 384 + c;
    float s = 0.0f;
#pragma unroll
    for (int nc = 0; nc < 16; nc++) s += p[nc * 384];
    r[id] = s;
}

// K4: talking heads (8x8 fp32) + LIF over t -> kvs[t,b,c] bf16 {0,1} mask
__global__ void talking_kernel(const float* __restrict__ r, const float* __restrict__ th,
                               u16* __restrict__ kvs) {
    int id = blockIdx.x * 256 + threadIdx.x;
    if (id >= 8 * 384) return;
    int b = id / 384, c = id % 384;
    int oh = c / 48, d = c % 48;
    float v = 0.0f;
    for (int t = 0; t < 4; t++) {
        const float* rr = r + (t * 8 + b) * 384 + d;
        float s = 0.0f;
#pragma unroll
        for (int h = 0; h < 8; h++) s = __fmaf_rn(th[oh * 8 + h], rr[h * 48], s);
        v = __fadd_rn(v, __fmul_rn(__fsub_rn(s, v), 0.5f));
        bool sp = (v >= 0.5f);
        v = sp ? 0.0f : v;
        kvs[(t * 8 + b) * 384 + c] = sp ? SPIKE_B : (u16)0;
    }
}

// ---------------------------------------------------------------------------
// K5: proj conv (K=384 bf16) + fused kvs gate + bias + BN + residual.
// 128x128 tiles, ring-of-2, issue-early prefetch (T14), reg-dbuf k-halves,
// ONE barrier/tile, BN tables in LDS. grid (nt=8, mt=3, tb=32), 2 blk/CU.
// ---------------------------------------------------------------------------
__global__ __launch_bounds__(256, 2) void proj_kernel(
    const u16* __restrict__ Aproj, const u16* __restrict__ qs, const u16* __restrict__ kvs,
    const float* __restrict__ xin,
    const float* __restrict__ pb, const float* __restrict__ pg, const float* __restrict__ pbe,
    const float* __restrict__ pm, const float* __restrict__ pv, float* __restrict__ out) {
    __shared__ __align__(16) u16 At[2][8192];
    __shared__ __align__(16) u16 Bt[2][8192];
    __shared__ float eS[128], eM[128], eB[128], eBi[128];

    int tb = blockIdx.z, mt = blockIdx.y, nt = blockIdx.x;
    int m0 = mt * 128, n0 = nt * 128;
    int tid = threadIdx.x, wave = tid >> 6, lane = tid & 63;
    int l15 = lane & 15, quad = lane >> 4;
    int wm = (wave & 1) * 64, wn = (wave >> 1) * 64;

    const u16* Bsrc = qs + ((size_t)(tb * 1024 + n0)) * 384;
    const u16* mbase = kvs + tb * 384;

    if (tid < 128) {
        int o = m0 + tid;
        eS[tid] = pg[o] / sqrtf(pv[o] + 1e-5f);
        eM[tid] = pm[o];
        eB[tid] = pbe[o];
        eBi[tid] = pb[o];
    }

    auto stage = [&](int s) {
        int kk = s * 64;
        int buf = s & 1;
#pragma unroll
        for (int ii = 0; ii < 4; ii++) {
            int l = ii * 256 + tid;
            int row = l >> 3;
            int cs = (l & 7) ^ (row & 7);
            async16(Aproj + (size_t)(m0 + row) * 384 + kk + cs * 8, &At[buf][l * 8]);
            async16(Bsrc + (size_t)row * 384 + kk + cs * 8, &Bt[buf][l * 8]);
        }
    };

    f32x4 acc[4][4];
#pragma unroll
    for (int i = 0; i < 4; i++)
#pragma unroll
        for (int j = 0; j < 4; j++) acc[i][j] = (f32x4){0.f, 0.f, 0.f, 0.f};

    stage(0);
    __syncthreads();  // stage0 landed + tables published

#pragma unroll 1
    for (int kkb = 0; kkb < 6; kkb++) {
        int buf = kkb & 1;
        int kk = kkb * 64;
        // issue next tile FIRST: its vmcnt(0) drain at tile end hides under
        // this tile's reads + 32 MFMAs (buf^1's readers done at end of kkb-1)
        if (kkb < 5) stage(kkb + 1);
        __builtin_amdgcn_sched_barrier(0);

        short8v msk0 = *(const short8v*)(mbase + kk + quad * 8);
        short8v msk1 = *(const short8v*)(mbase + kk + (4 + quad) * 8);
        short8v afA[4], bfA[4], afB[4], bfB[4];
#pragma unroll
        for (int i = 0; i < 4; i++) {
            int row = wm + i * 16 + l15;
            afA[i] = *(const short8v*)&At[buf][row * 64 + ((quad) ^ (row & 7)) * 8];
            afB[i] = *(const short8v*)&At[buf][row * 64 + ((4 + quad) ^ (row & 7)) * 8];
        }
#pragma unroll
        for (int j = 0; j < 4; j++) {
            int nr = wn + j * 16 + l15;
            bfA[j] = *(const short8v*)&Bt[buf][nr * 64 + ((quad) ^ (nr & 7)) * 8] & msk0;
            bfB[j] = *(const short8v*)&Bt[buf][nr * 64 + ((4 + quad) ^ (nr & 7)) * 8] & msk1;
        }
        __builtin_amdgcn_sched_barrier(0);
        __builtin_amdgcn_s_setprio(1);
#pragma unroll
        for (int i = 0; i < 4; i++)
#pragma unroll
            for (int j = 0; j < 4; j++) acc[i][j] = mfma_bf16(afA[i], bfA[j], acc[i][j]);
        __builtin_amdgcn_s_setprio(0);
        __builtin_amdgcn_sched_barrier(0);
        __builtin_amdgcn_s_setprio(1);
#pragma unroll
        for (int i = 0; i < 4; i++)
#pragma unroll
            for (int j = 0; j < 4; j++) acc[i][j] = mfma_bf16(afB[i], bfB[j], acc[i][j]);
        __builtin_amdgcn_s_setprio(0);
        // publish buf^1 for tile kkb+1 (ring-of-2: nothing newer to count)
        if (kkb < 5) asm volatile("s_waitcnt vmcnt(0)\n\ts_barrier" ::: "memory");
    }

    // epilogue: y = conv+bias; (y-mean)*scale+beta; + identity (numpy order)
#pragma unroll
    for (int i = 0; i < 4; i++) {
#pragma unroll
        for (int e = 0; e < 4; e++) {
            int co = wm + i * 16 + quad * 4 + e;
            int o = m0 + co;
            float scale = eS[co], mean = eM[co], beta = eB[co], bias = eBi[co];
#pragma unroll
            for (int j = 0; j < 4; j++) {
                int n = n0 + wn + j * 16 + l15;
                size_t idx = ((size_t)tb * 384 + o) * 1024 + n;
                float y = __fadd_rn(acc[i][j][e], bias);
                y = __fadd_rn(__fmul_rn(__fsub_rn(y, mean), scale), beta);
                out[idx] = __fadd_rn(y, xin[idx]);
            }
        }
    }
}

// ---------------------------------------------------------------------------
extern "C" void kernel_launch(void* const* d_in, const int* in_sizes, int n_in,
                              void* d_out, int out_size, void* d_ws, size_t ws_size,
                              hipStream_t stream) {
    (void)in_sizes; (void)n_in; (void)out_size; (void)ws_size;
    const float* x  = (const float*)d_in[0];
    const float* qw = (const float*)d_in[1];
    const float* kw = (const float*)d_in[2];
    const float* vw = (const float*)d_in[3];
    const float* th = (const float*)d_in[4];
    const float* pw = (const float*)d_in[5];
    const float* pb = (const float*)d_in[6];
    const float* qg = (const float*)d_in[7],  *qbe = (const float*)d_in[8];
    const float* qm = (const float*)d_in[9],  *qv  = (const float*)d_in[10];
    const float* kg = (const float*)d_in[11], *kbe = (const float*)d_in[12];
    const float* km = (const float*)d_in[13], *kv_ = (const float*)d_in[14];
    const float* vg = (const float*)d_in[15], *vbe = (const float*)d_in[16];
    const float* vm = (const float*)d_in[17], *vv_ = (const float*)d_in[18];
    const float* pg = (const float*)d_in[19], *pbe = (const float*)d_in[20];
    const float* pm = (const float*)d_in[21], *pv  = (const float*)d_in[22];
    float* out = (float*)d_out;

    char* w = (char*)d_ws;
    const size_t SPIKES = (size_t)32 * 1024 * 384 * 2;  // 25,165,824 B each
    u16* xs    = (u16*)(w);
    u16* qs    = (u16*)(w + SPIKES);
    u16* ks    = (u16*)(w + 2 * SPIKES);
    u16* vs    = (u16*)(w + 3 * SPIKES);
    u16* Ah    = (u16*)(w + 4 * SPIKES);                         // 1,769,472 B
    u16* Aproj = (u16*)(w + 4 * SPIKES + 1769472);               //   294,912 B
    float* r2  = (float*)(w + 4 * SPIKES + 1769472 + 294912);    //   786,432 B
    float* r   = (float*)(w + 4 * SPIKES + 1769472 + 294912 + 786432);  // 49,152 B
    u16* kvs   = (u16*)(w + 4 * SPIKES + 1769472 + 294912 + 786432 + 49152);  // 24,576 B

    prep_kernel<<<1728, 256, 0, stream>>>(qw, kw, vw, pw, Ah, Aproj);
    lifx_kernel<<<dim3(16, 6, 8), 256, 0, stream>>>(x, xs);
    qkv_kernel<<<dim3(16, 9, 8), 512, 0, stream>>>(Ah, xs, qs, ks, vs,
                                                   qg, qbe, qm, qv,
                                                   kg, kbe, km, kv_,
                                                   vg, vbe, vm, vv_);
    kvred_kernel<<<dim3(16, 32), 384, 0, stream>>>(ks, vs, r2);
    ncsum_kernel<<<48, 256, 0, stream>>>(r2, r);
    talking_kernel<<<12, 256, 0, stream>>>(r, th, kvs);
    proj_kernel<<<dim3(8, 3, 32), 256, 0, stream>>>(Aproj, qs, kvs, x, pb, pg, pbe, pm, pv, out);
}